// Round 1
// baseline (187.797 us; speedup 1.0000x reference)
//
#include <hip/hip_runtime.h>
#include <hip/hip_bf16.h>

#define NROW 8192
#define NDIM 128

typedef __attribute__((ext_vector_type(8))) short short8;
typedef __attribute__((ext_vector_type(4))) float f32x4;

// Monotone float<->uint map so atomicMin/atomicMax on uint implement fp min/max.
__device__ __forceinline__ unsigned f2u_mono(float f) {
  unsigned u = __float_as_uint(f);
  return (u & 0x80000000u) ? ~u : (u | 0x80000000u);
}
__device__ __forceinline__ float u2f_mono(unsigned u) {
  return __uint_as_float((u & 0x80000000u) ? (u ^ 0x80000000u) : ~u);
}
__device__ __forceinline__ unsigned short f2bf(float f) {  // RTN fp32->bf16
  unsigned u = __float_as_uint(f);
  u += 0x7fffu + ((u >> 16) & 1u);
  return (unsigned short)(u >> 16);
}

__global__ __launch_bounds__(256) void k_convert(const float* __restrict__ e,
                                                 unsigned short* __restrict__ h) {
  int i = (blockIdx.x * 256 + threadIdx.x) * 8;
  float4 f0 = *reinterpret_cast<const float4*>(e + i);
  float4 f1 = *reinterpret_cast<const float4*>(e + i + 4);
  ushort4 a, b;
  a.x = f2bf(f0.x); a.y = f2bf(f0.y); a.z = f2bf(f0.z); a.w = f2bf(f0.w);
  b.x = f2bf(f1.x); b.y = f2bf(f1.y); b.z = f2bf(f1.z); b.w = f2bf(f1.w);
  *reinterpret_cast<ushort4*>(h + i) = a;
  *reinterpret_cast<ushort4*>(h + i + 4) = b;
}

// Fused sim-tile GEMM + per-row masked reductions.
// Swapped orientation: A-operand = col-tile rows of E, B-operand = row-tile rows of E,
// so D[a][b] = sim[rowBase + n*16 + (lane&15)][colBase + m*16 + (lane>>4)*4 + reg]:
// each lane's 16 values (m x reg) all belong to ONE output row -> row reduce is
// local + shfl_xor(16) + shfl_xor(32).
template <int PASS>
__global__ __launch_bounds__(256) void k_sim(
    const unsigned short* __restrict__ eh, const int* __restrict__ labels,
    unsigned* __restrict__ pminu, unsigned* __restrict__ nmaxu,
    float* __restrict__ s_ap, float* __restrict__ s_hp,
    float* __restrict__ s_an, float* __restrict__ s_hn) {
  __shared__ unsigned short Lr[128 * 128];  // E rows [rowBase,+128), XOR-swizzled
  __shared__ unsigned short Lc[128 * 128];  // E rows [colBase,+128)

  const int t = threadIdx.x;
  const int rowBase = blockIdx.y * 128;
  const int colBase = blockIdx.x * 128;

  {  // stage: 16B per thread per tile-chunk; swizzle byte ^= ((row&7)<<4)
    const uint4* gr = reinterpret_cast<const uint4*>(eh + (size_t)rowBase * NDIM);
    const uint4* gc = reinterpret_cast<const uint4*>(eh + (size_t)colBase * NDIM);
#pragma unroll
    for (int it = 0; it < 8; ++it) {
      int idx = it * 256 + t;
      int r = idx >> 4;
      int c8 = idx & 15;
      int dst = r * 256 + ((c8 * 16) ^ ((r & 7) << 4));
      *reinterpret_cast<uint4*>(reinterpret_cast<char*>(Lr) + dst) = gr[idx];
      *reinterpret_cast<uint4*>(reinterpret_cast<char*>(Lc) + dst) = gc[idx];
    }
  }

  const int lane = t & 63;
  const int wid = t >> 6;
  const int wr = wid >> 1;  // output-row 64-half
  const int wc = wid & 1;   // output-col 64-half
  const int g = lane >> 4;
  const int l15 = lane & 15;

  __syncthreads();

  f32x4 acc[4][4];
#pragma unroll
  for (int m = 0; m < 4; ++m)
#pragma unroll
    for (int n = 0; n < 4; ++n) acc[m][n] = (f32x4){0.f, 0.f, 0.f, 0.f};

#pragma unroll
  for (int kk = 0; kk < 4; ++kk) {
    const int kb = kk * 64 + g * 16;
    short8 av[4], bv[4];
#pragma unroll
    for (int m = 0; m < 4; ++m) {
      int R = wc * 64 + m * 16 + l15;
      av[m] = *reinterpret_cast<const short8*>(
          reinterpret_cast<const char*>(Lc) + R * 256 + (kb ^ ((R & 7) << 4)));
    }
#pragma unroll
    for (int n = 0; n < 4; ++n) {
      int R = wr * 64 + n * 16 + l15;
      bv[n] = *reinterpret_cast<const short8*>(
          reinterpret_cast<const char*>(Lr) + R * 256 + (kb ^ ((R & 7) << 4)));
    }
#pragma unroll
    for (int m = 0; m < 4; ++m)
#pragma unroll
      for (int n = 0; n < 4; ++n)
        acc[m][n] = __builtin_amdgcn_mfma_f32_16x16x32_bf16(av[m], bv[n], acc[m][n], 0, 0, 0);
  }

  // labels (loaded after MFMA loop to keep live-range short; L2-hot)
  int lcv[4][4];
#pragma unroll
  for (int m = 0; m < 4; ++m)
#pragma unroll
    for (int r = 0; r < 4; ++r)
      lcv[m][r] = labels[colBase + wc * 64 + m * 16 + g * 4 + r];

#pragma unroll
  for (int n = 0; n < 4; ++n) {
    const int grow = rowBase + wr * 64 + n * 16 + l15;
    const int lr = labels[grow];
    if (PASS == 1) {
      float pmin = INFINITY, nmax = -INFINITY;
#pragma unroll
      for (int m = 0; m < 4; ++m) {
#pragma unroll
        for (int r = 0; r < 4; ++r) {
          float s = acc[m][n][r];
          int gcol = colBase + wc * 64 + m * 16 + g * 4 + r;
          bool eq = (lr == lcv[m][r]);
          bool dg = (grow == gcol);
          if (eq && !dg) pmin = fminf(pmin, s);
          if (!eq) nmax = fmaxf(nmax, s);
        }
      }
      pmin = fminf(pmin, __shfl_xor(pmin, 16));
      pmin = fminf(pmin, __shfl_xor(pmin, 32));
      nmax = fmaxf(nmax, __shfl_xor(nmax, 16));
      nmax = fmaxf(nmax, __shfl_xor(nmax, 32));
      if (g == 0) {
        if (pmin < INFINITY) atomicMin(&pminu[grow], f2u_mono(pmin));
        if (nmax > -INFINITY) atomicMax(&nmaxu[grow], f2u_mono(nmax));
      }
    } else {
      // untouched rows decode to NaN -> comparisons false -> hard sums stay 0 (fallback)
      const float pmin = u2f_mono(pminu[grow]);
      const float nmax = u2f_mono(nmaxu[grow]);
      float ap = 0.f, hp = 0.f, an = 0.f, hn = 0.f;
#pragma unroll
      for (int m = 0; m < 4; ++m) {
#pragma unroll
        for (int r = 0; r < 4; ++r) {
          float s = acc[m][n][r];
          int gcol = colBase + wc * 64 + m * 16 + g * 4 + r;
          bool eq = (lr == lcv[m][r]);
          bool dg = (grow == gcol);
          float ep = __expf(1.0f - 2.0f * s);   // exp(-ALPHA*(s-BASE))
          float en = __expf(50.0f * s - 25.0f); // exp(BETA*(s-BASE))
          if (eq && !dg) {
            ap += ep;
            if (s - 0.1f < nmax) hp += ep;
          }
          if (!eq) {
            an += en;
            if (s + 0.1f > pmin) hn += en;
          }
        }
      }
      ap += __shfl_xor(ap, 16); ap += __shfl_xor(ap, 32);
      hp += __shfl_xor(hp, 16); hp += __shfl_xor(hp, 32);
      an += __shfl_xor(an, 16); an += __shfl_xor(an, 32);
      hn += __shfl_xor(hn, 16); hn += __shfl_xor(hn, 32);
      if (g == 0) {
        if (ap > 0.f) atomicAdd(&s_ap[grow], ap);
        if (hp > 0.f) atomicAdd(&s_hp[grow], hp);
        if (an > 0.f) atomicAdd(&s_an[grow], an);
        if (hn > 0.f) atomicAdd(&s_hn[grow], hn);
      }
    }
  }
}

__global__ __launch_bounds__(256) void k_final(
    const float* __restrict__ s_ap, const float* __restrict__ s_hp,
    const float* __restrict__ s_an, const float* __restrict__ s_hn,
    float* __restrict__ out) {
  const int t = threadIdx.x;
  float acc = 0.f, cnt = 0.f;
  for (int i = t; i < NROW; i += 256) {
    float ap = s_ap[i], hp = s_hp[i], an = s_an[i], hn = s_hn[i];
    bool valid = (ap > 0.f) && (an > 0.f);
    float ps = (hp > 0.f) ? hp : ap;
    float ns = (hn > 0.f) ? hn : an;
    float loss = 0.5f * log1pf(ps) + 0.02f * log1pf(ns);
    if (valid) { acc += loss; cnt += 1.f; }
  }
#pragma unroll
  for (int o = 32; o > 0; o >>= 1) {
    acc += __shfl_down(acc, o);
    cnt += __shfl_down(cnt, o);
  }
  __shared__ float sa[4], sc[4];
  int w = t >> 6, lane = t & 63;
  if (lane == 0) { sa[w] = acc; sc[w] = cnt; }
  __syncthreads();
  if (t == 0) {
    float A = sa[0] + sa[1] + sa[2] + sa[3];
    float C = sc[0] + sc[1] + sc[2] + sc[3];
    out[0] = A / fmaxf(C, 1.f);
  }
}

extern "C" void kernel_launch(void* const* d_in, const int* in_sizes, int n_in,
                              void* d_out, int out_size, void* d_ws, size_t ws_size,
                              hipStream_t stream) {
  const float* emb = (const float*)d_in[0];
  const int* labels = (const int*)d_in[1];
  float* out = (float*)d_out;

  // ws layout: [bf16 emb: 2MB][pminu:32K][nmaxu:32K][ap|hp|an|hn: 4x32K] = ~2.2MB
  unsigned short* embh = (unsigned short*)d_ws;
  unsigned* pminu = (unsigned*)((char*)d_ws + (size_t)NROW * NDIM * 2);
  unsigned* nmaxu = pminu + NROW;
  float* s_ap = (float*)(nmaxu + NROW);
  float* s_hp = s_ap + NROW;
  float* s_an = s_hp + NROW;
  float* s_hn = s_an + NROW;

  hipMemsetAsync(pminu, 0xFF, (size_t)NROW * 4, stream);          // mapped +inf sentinel
  hipMemsetAsync(nmaxu, 0, (size_t)NROW * 4 * 5, stream);         // nmaxu + 4 sums = 0

  k_convert<<<NROW * NDIM / (256 * 8), 256, 0, stream>>>(emb, embh);
  dim3 grid(64, 64);
  k_sim<1><<<grid, 256, 0, stream>>>(embh, labels, pminu, nmaxu, s_ap, s_hp, s_an, s_hn);
  k_sim<2><<<grid, 256, 0, stream>>>(embh, labels, pminu, nmaxu, s_ap, s_hp, s_an, s_hn);
  k_final<<<1, 256, 0, stream>>>(s_ap, s_hp, s_an, s_hn, out);
}